// Round 7
// baseline (240.627 us; speedup 1.0000x reference)
//
#include <hip/hip_runtime.h>
#include <math.h>

// Problem constants (from reference)
#define B_ 16
#define T_ 12
#define F_ 32
#define N_ 500
#define L_ 3
#define K_ 2
#define INV_N1 (1.0f / 501.0f)

__device__ __forceinline__ float sigmoidf_(float x) {
    return 1.f / (1.f + __expf(-x));
}

// ---------------------------------------------------------------------------
// Prep kernel. grid = B_*T_ (192) blocks x 256 threads.
// Per block bt: colsum0[bt][f] = sum_n x0[bt][f][n] (float4, butterfly over 8
// j-lanes); zero cs1/cs2 slices. Blocks 0..2 additionally fold
// Wc[li] = (gcn_w[li] @ gate_w) / (N+1), bc[li] = gcn_b[li] @ gate_w + gate_b.
// ---------------------------------------------------------------------------
__global__ __launch_bounds__(256) void prep_kernel(
        const float* __restrict__ x0,
        const float* __restrict__ gcn_w, const float* __restrict__ gcn_b,
        const float* __restrict__ gate_w, const float* __restrict__ gate_b,
        float* __restrict__ Wc, float* __restrict__ bc,
        float* __restrict__ cs0, float* __restrict__ cs1,
        float* __restrict__ cs2) {
    const int bt = blockIdx.x;
    const int tid = threadIdx.x;

    if (tid < F_) {  // zero next-layer colsum accumulators
        cs1[bt * F_ + tid] = 0.f;
        cs2[bt * F_ + tid] = 0.f;
    }

    // colsum of x0 for layer 0
    const int f = tid >> 3, j = tid & 7;
    const float4* row = (const float4*)(x0 + ((size_t)bt * F_ + f) * N_);
    float s = 0.f;
    for (int j4 = j; j4 < 125; j4 += 8) {
        float4 v = row[j4];
        s += v.x + v.y + v.z + v.w;
    }
    s += __shfl_xor(s, 1, 64);
    s += __shfl_xor(s, 2, 64);
    s += __shfl_xor(s, 4, 64);
    if (j == 0) cs0[bt * F_ + f] = s;

    // weight folds (blocks 0..2)
    if (bt < L_) {
        const int li = bt;
        for (int idx = tid; idx < F_ * F_; idx += 256) {
            int fi = idx >> 5, fo = idx & 31;
            float a = 0.f;
#pragma unroll
            for (int m = 0; m < F_; ++m)
                a += gcn_w[(li * F_ + fi) * F_ + m] * gate_w[m * F_ + fo];
            Wc[li * F_ * F_ + idx] = a * INV_N1;
        }
        if (tid < F_) {
            float a = gate_b[tid];
#pragma unroll
            for (int m = 0; m < F_; ++m)
                a += gcn_b[li * F_ + m] * gate_w[m * F_ + tid];
            bc[li * F_ + tid] = a;
        }
    }
}

// ---------------------------------------------------------------------------
// Fused layer kernel: gcn+gate (recomputed for both conv taps, in LDS) +
// causal dilated conv + bias + relu + residual + res stash + next colsum.
// grid = B_*T_*4 (768) blocks x 512 threads. Block = (bt, 128-node chunk).
// LDS: A = x tile then g_prev tile (in place); Bt = g_cur tile.
// xin != xout (ping-pong) because block (bt) reads xin[bt] AND xin[bt-dil].
// ---------------------------------------------------------------------------
__global__ __launch_bounds__(512, 6) void layer_kernel(
        const float* __restrict__ xin, float* __restrict__ xout,
        const float* __restrict__ conv_w, const float* __restrict__ conv_b,
        const float* __restrict__ Wc, const float* __restrict__ bc,
        const float* __restrict__ cs, int li, int dil,
        float* __restrict__ resP, float* __restrict__ cs_next, int do_cs) {
    __shared__ __align__(16) float A[F_][128];    // x tile -> g_prev tile
    __shared__ __align__(16) float Bt[F_][128];   // g_cur tile
    __shared__ __align__(16) float sW[F_ * F_ * K_];
    __shared__ __align__(16) float sWc[F_ * F_];
    __shared__ float sbase[2][F_];
    __shared__ float sB[F_];

    const int blk = blockIdx.x;
    const int bt = blk >> 2, c = blk & 3;
    const int t = bt % T_, b = bt / T_;
    const int nbase = c * 128;
    const int nb4 = (c == 3) ? 29 : 32;   // float4s per feature row this chunk
    const int tid = threadIdx.x;
    const bool hasprev = (t >= dil);      // block-uniform

    // stage conv weights (2048 floats = 512 float4, one per thread)
    ((float4*)sW)[tid] = ((const float4*)(conv_w + (size_t)li * F_ * F_ * K_))[tid];
    if (tid < 256)
        ((float4*)sWc)[tid] = ((const float4*)(Wc + li * F_ * F_))[tid];
    if (tid < F_) sB[tid] = conv_b[li * F_ + tid];
    // base vectors: base = bc + colsum . Wc  (for bt and bt-dil)
    if (tid >= 320 && tid < 320 + F_) {
        const int fo = tid - 320;
        const float* cw = Wc + li * F_ * F_;
        float a = bc[li * F_ + fo];
#pragma unroll
        for (int fi = 0; fi < F_; ++fi) a += cs[bt * F_ + fi] * cw[fi * F_ + fo];
        sbase[0][fo] = a;
    }
    if (hasprev && tid >= 384 && tid < 384 + F_) {
        const int fo = tid - 384;
        const float* cw = Wc + li * F_ * F_;
        float a = bc[li * F_ + fo];
#pragma unroll
        for (int fi = 0; fi < F_; ++fi)
            a += cs[(bt - dil) * F_ + fi] * cw[fi * F_ + fo];
        sbase[1][fo] = a;
    }
    // stage x_cur tile
    for (int idx = tid; idx < F_ * nb4; idx += 512) {
        int f = idx / nb4, j4 = idx % nb4;
        ((float4*)&A[f][0])[j4] =
            *(const float4*)(xin + ((size_t)bt * F_ + f) * N_ + nbase + 4 * j4);
    }
    __syncthreads();

    const int n = tid & 127, q = tid >> 7;
    const int gn = nbase + n;
    const bool valid = (gn < N_);
    const int fo0 = q * 8;

    // residual copy (before A is overwritten) + g_cur into Bt
    float rv[8], gc[8];
#pragma unroll
    for (int jj = 0; jj < 8; ++jj) {
        rv[jj] = A[fo0 + jj][n];
        gc[jj] = sbase[0][fo0 + jj];
    }
#pragma unroll
    for (int fi = 0; fi < F_; ++fi) {
        float xv = A[fi][n];
#pragma unroll
        for (int jj = 0; jj < 8; ++jj) gc[jj] += xv * sWc[fi * F_ + fo0 + jj];
    }
#pragma unroll
    for (int jj = 0; jj < 8; ++jj) Bt[fo0 + jj][n] = sigmoidf_(gc[jj]);

    if (hasprev) {
        __syncthreads();  // all reads of A (x_cur) complete
        for (int idx = tid; idx < F_ * nb4; idx += 512) {
            int f = idx / nb4, j4 = idx % nb4;
            ((float4*)&A[f][0])[j4] = *(const float4*)(
                xin + ((size_t)(bt - dil) * F_ + f) * N_ + nbase + 4 * j4);
        }
        __syncthreads();
        float gp[8];
#pragma unroll
        for (int jj = 0; jj < 8; ++jj) gp[jj] = sbase[1][fo0 + jj];
#pragma unroll
        for (int fi = 0; fi < F_; ++fi) {
            float xv = A[fi][n];
#pragma unroll
            for (int jj = 0; jj < 8; ++jj) gp[jj] += xv * sWc[fi * F_ + fo0 + jj];
        }
        __syncthreads();  // all reads of A (x_prev) complete before overwrite
#pragma unroll
        for (int jj = 0; jj < 8; ++jj) A[fo0 + jj][n] = sigmoidf_(gp[jj]);
    }
    __syncthreads();  // Bt (and A = g_prev if hasprev) ready

    // conv: out = relu(bias + sum_fi gprev*w0 + gcur*w1)
    float acc[8];
#pragma unroll
    for (int jj = 0; jj < 8; ++jj) acc[jj] = sB[fo0 + jj];
    if (hasprev) {
#pragma unroll
        for (int fi = 0; fi < F_; ++fi) {
            float gpv = A[fi][n], gcv = Bt[fi][n];
#pragma unroll
            for (int jj = 0; jj < 8; ++jj)
                acc[jj] += gpv * sW[((fo0 + jj) * F_ + fi) * K_ + 0]
                         + gcv * sW[((fo0 + jj) * F_ + fi) * K_ + 1];
        }
    } else {
#pragma unroll
        for (int fi = 0; fi < F_; ++fi) {
            float gcv = Bt[fi][n];
#pragma unroll
            for (int jj = 0; jj < 8; ++jj)
                acc[jj] += gcv * sW[((fo0 + jj) * F_ + fi) * K_ + 1];
        }
    }

    float xov[8];
#pragma unroll
    for (int jj = 0; jj < 8; ++jj) xov[jj] = 0.f;
    if (valid) {
#pragma unroll
        for (int jj = 0; jj < 8; ++jj) {
            float o = fmaxf(acc[jj], 0.f);
            float xo = o + rv[jj];
            xout[((size_t)bt * F_ + fo0 + jj) * N_ + gn] = xo;
            acc[jj] = o;   // relu output for res stash
            xov[jj] = xo;  // for colsum
        }
        if (t == T_ - 1) {
            float* rs = resP + ((size_t)(li * B_ + b) * N_ + gn) * F_ + fo0;
#pragma unroll
            for (int jj = 0; jj < 8; ++jj) rs[jj] = acc[jj];
        }
    }

    // colsum of xout for next layer (invalid lanes contribute 0)
    if (do_cs) {
        const int lane = tid & 63;
#pragma unroll
        for (int jj = 0; jj < 8; ++jj) {
            float s = xov[jj];
#pragma unroll
            for (int off = 32; off >= 1; off >>= 1) s += __shfl_xor(s, off, 64);
            if (lane == 0) atomicAdd(&cs_next[bt * F_ + fo0 + jj], s);
        }
    }
}

// ---------------------------------------------------------------------------
// Fused attention. grid = B_*N_/2 (4000) blocks x 192 threads.
// res layout resP[l][b][n][f] (f contiguous). Stage 1: 6 groups of 32 lanes
// compute score(b, l, n) with the reference's reshape quirk (j=n*3+l ->
// l'=j/500, n'=j%500). Stage 2: softmax over L + weighted combine.
// ---------------------------------------------------------------------------
__global__ __launch_bounds__(192) void att_kernel(
        const float* __restrict__ resP,
        const float* __restrict__ Wa, const float* __restrict__ ba,
        const float* __restrict__ v, float* __restrict__ out) {
    __shared__ __align__(16) float sWa[F_ * F_];
    __shared__ float sScore[2][L_];
    const int tid = threadIdx.x;
    for (int idx = tid; idx < F_ * F_; idx += 192) sWa[idx] = Wa[idx];
    __syncthreads();

    const int pair = blockIdx.x;
    const int b = pair / 250;
    const int base_n = (pair % 250) * 2;
    const int gIdx = tid >> 5;  // 0..5
    const int fo = tid & 31;
    const int o = gIdx / 3, l = gIdx % 3;
    const int n = base_n + o;
    const int j = n * 3 + l;
    const int lp = j / N_, np = j % N_;

    const float vv = v[fo];
    const float* r = resP + ((size_t)(lp * B_ + b) * N_ + np) * F_;
    float acc = ba[fo];
#pragma unroll
    for (int f = 0; f < F_; ++f) acc += r[f] * sWa[f * F_ + fo];
    float s = tanhf(acc) * vv;
#pragma unroll
    for (int off = 16; off >= 1; off >>= 1) s += __shfl_xor(s, off, 64);
    if (fo == 0) sScore[o][l] = s;
    __syncthreads();

    if (tid < 64) {
        const int oo = tid >> 5, f = tid & 31;
        const int nn = base_n + oo;
        const float s0 = sScore[oo][0], s1 = sScore[oo][1], s2 = sScore[oo][2];
        const float m = fmaxf(fmaxf(s0, s1), s2);
        const float e0 = __expf(s0 - m), e1 = __expf(s1 - m), e2 = __expf(s2 - m);
        const float inv = 1.f / (e0 + e1 + e2);
        const float r0 = resP[((size_t)(0 * B_ + b) * N_ + nn) * F_ + f];
        const float r1 = resP[((size_t)(1 * B_ + b) * N_ + nn) * F_ + f];
        const float r2 = resP[((size_t)(2 * B_ + b) * N_ + nn) * F_ + f];
        out[(size_t)(b * N_ + nn) * F_ + f] = (e0 * r0 + e1 * r1 + e2 * r2) * inv;
    }
}

// ---------------------------------------------------------------------------
extern "C" void kernel_launch(void* const* d_in, const int* in_sizes, int n_in,
                              void* d_out, int out_size, void* d_ws, size_t ws_size,
                              hipStream_t stream) {
    const float* x0      = (const float*)d_in[0];   // node_embeddings (B,T,F,N)
    const float* conv_w  = (const float*)d_in[4];   // (L,F,F,1,K)
    const float* conv_b  = (const float*)d_in[5];   // (L,F)
    const float* gcn_w   = (const float*)d_in[6];   // (L,F,F)
    const float* gcn_b   = (const float*)d_in[7];   // (L,F)
    const float* gate_w  = (const float*)d_in[8];   // (F,F)
    const float* gate_b  = (const float*)d_in[9];   // (F,)
    const float* att_Wa  = (const float*)d_in[10];  // (F,F)
    const float* att_ba  = (const float*)d_in[11];  // (F,)
    const float* att_v   = (const float*)d_in[12];  // (F,1)

    float* ws = (float*)d_ws;
    float* xA   = ws;               // B*T*F*N = 3,072,000
    float* xB   = xA + 3072000;     // 3,072,000
    float* resP = xB + 3072000;     // L*B*N*F = 768,000
    float* Wc   = resP + 768000;    // 3*32*32 = 3072
    float* bc   = Wc + 3072;        // 96
    float* cs0  = bc + 96;          // B*T*F = 6144
    float* cs1  = cs0 + 6144;       // 6144
    float* cs2  = cs1 + 6144;       // 6144
    // total ~28 MB

    prep_kernel<<<B_ * T_, 256, 0, stream>>>(x0, gcn_w, gcn_b, gate_w, gate_b,
                                             Wc, bc, cs0, cs1, cs2);

    // ping-pong layer buffers (fused kernel reads xin[bt] and xin[bt-dil])
    layer_kernel<<<B_ * T_ * 4, 512, 0, stream>>>(x0, xA, conv_w, conv_b,
                                                  Wc, bc, cs0, 0, 1,
                                                  resP, cs1, 1);
    layer_kernel<<<B_ * T_ * 4, 512, 0, stream>>>(xA, xB, conv_w, conv_b,
                                                  Wc, bc, cs1, 1, 2,
                                                  resP, cs2, 1);
    layer_kernel<<<B_ * T_ * 4, 512, 0, stream>>>(xB, xA, conv_w, conv_b,
                                                  Wc, bc, cs2, 2, 4,
                                                  resP, cs1, 0);

    att_kernel<<<(B_ * N_) / 2, 192, 0, stream>>>(resP, att_Wa, att_ba, att_v,
                                                  (float*)d_out);
}

// Round 13
// 184.860 us; speedup vs baseline: 1.3017x; 1.3017x over previous
//
#include <hip/hip_runtime.h>
#include <math.h>

// Problem constants (from reference)
#define B_ 16
#define T_ 12
#define F_ 32
#define N_ 500
#define L_ 3
#define K_ 2
#define INV_N1 (1.0f / 501.0f)

__device__ __forceinline__ float sigmoidf_(float x) {
    return 1.f / (1.f + __expf(-x));
}

// ---------------------------------------------------------------------------
// Prep kernel. grid = B_*T_ (192) blocks x 256 threads.
// Zero cs1/cs2 (atomic accumulators). colsum0[bt][f] = sum_n x0[bt][f][n] for
// active timesteps (t >= 4; earlier ones are dead in the dependence cone).
// Blocks 0..2 fold Wc = (gcn_w @ gate_w)/(N+1), bc = gcn_b@gate_w + gate_b.
// ---------------------------------------------------------------------------
__global__ __launch_bounds__(256) void prep_kernel(
        const float* __restrict__ x0,
        const float* __restrict__ gcn_w, const float* __restrict__ gcn_b,
        const float* __restrict__ gate_w, const float* __restrict__ gate_b,
        float* __restrict__ Wc, float* __restrict__ bc,
        float* __restrict__ cs0, float* __restrict__ cs1,
        float* __restrict__ cs2) {
    const int bt = blockIdx.x;
    const int tid = threadIdx.x;
    const int t = bt % T_;

    if (tid < F_) {  // zero next-layer colsum accumulators
        cs1[bt * F_ + tid] = 0.f;
        cs2[bt * F_ + tid] = 0.f;
    }

    // colsum of x0 for layer 0 (only t >= 4 is ever consumed)
    if (t >= 4) {
        const int f = tid >> 3, j = tid & 7;
        const float4* row = (const float4*)(x0 + ((size_t)bt * F_ + f) * N_);
        float s = 0.f;
        for (int j4 = j; j4 < 125; j4 += 8) {
            float4 v = row[j4];
            s += v.x + v.y + v.z + v.w;
        }
        s += __shfl_xor(s, 1, 64);
        s += __shfl_xor(s, 2, 64);
        s += __shfl_xor(s, 4, 64);
        if (j == 0) cs0[bt * F_ + f] = s;
    }

    // weight folds (blocks 0..2)
    if (bt < L_) {
        const int li = bt;
        for (int idx = tid; idx < F_ * F_; idx += 256) {
            int fi = idx >> 5, fo = idx & 31;
            float a = 0.f;
#pragma unroll
            for (int m = 0; m < F_; ++m)
                a += gcn_w[(li * F_ + fi) * F_ + m] * gate_w[m * F_ + fo];
            Wc[li * F_ * F_ + idx] = a * INV_N1;
        }
        if (tid < F_) {
            float a = gate_b[tid];
#pragma unroll
            for (int m = 0; m < F_; ++m)
                a += gcn_b[li * F_ + m] * gate_w[m * F_ + tid];
            bc[li * F_ + tid] = a;
        }
    }
}

// ---------------------------------------------------------------------------
// Fused layer kernel (round-7 structure, PASSED): gcn+gate recomputed for
// both conv taps in LDS + causal dilated conv + bias + relu + residual +
// res stash + next-layer colsum (atomicAdd).
// ACTIVE-TIMESTEP launch: grid = B_ * tcnt * 4; block -> (b, i, chunk) via
// XCD-aware swizzle; bt = b*T_ + tstart + i*tstep. All active t >= dil.
// xout == nullptr for the last layer (output unconsumed).
// ---------------------------------------------------------------------------
__global__ __launch_bounds__(512, 6) void layer_kernel(
        const float* __restrict__ xin, float* __restrict__ xout,
        const float* __restrict__ conv_w, const float* __restrict__ conv_b,
        const float* __restrict__ Wc, const float* __restrict__ bc,
        const float* __restrict__ cs, int li, int dil,
        float* __restrict__ resP, float* __restrict__ cs_next, int do_cs,
        int tstart, int tstep, int tcnt) {
    __shared__ __align__(16) float A[F_][128];    // x tile -> g_prev tile
    __shared__ __align__(16) float Bt[F_][128];   // g_cur tile
    __shared__ __align__(16) float sW[F_ * F_ * K_];
    __shared__ __align__(16) float sWc[F_ * F_];
    __shared__ float sbase[2][F_];
    __shared__ float sB[F_];

    // XCD-aware swizzle (gridDim.x divisible by 8): each XCD gets a
    // contiguous wid range -> 2 consecutive b's per XCD across layers.
    const int per = gridDim.x >> 3;
    const int wid = (blockIdx.x & 7) * per + (blockIdx.x >> 3);
    const int c = wid & 3;
    const int r = wid >> 2;
    const int b = r / tcnt, ti = r % tcnt;
    const int t = tstart + ti * tstep;
    const int bt = b * T_ + t;
    const int nbase = c * 128;
    const int nb4 = (c == 3) ? 29 : 32;   // float4s per feature row this chunk
    const int tid = threadIdx.x;
    const bool hasprev = (t >= dil);      // always true for active t's

    // stage conv weights (2048 floats = 512 float4, one per thread)
    ((float4*)sW)[tid] = ((const float4*)(conv_w + (size_t)li * F_ * F_ * K_))[tid];
    if (tid < 256)
        ((float4*)sWc)[tid] = ((const float4*)(Wc + li * F_ * F_))[tid];
    if (tid < F_) sB[tid] = conv_b[li * F_ + tid];
    // base vectors: base = bc + colsum . Wc  (for bt and bt-dil)
    if (tid >= 320 && tid < 320 + F_) {
        const int fo = tid - 320;
        const float* cw = Wc + li * F_ * F_;
        float a = bc[li * F_ + fo];
#pragma unroll
        for (int fi = 0; fi < F_; ++fi) a += cs[bt * F_ + fi] * cw[fi * F_ + fo];
        sbase[0][fo] = a;
    }
    if (hasprev && tid >= 384 && tid < 384 + F_) {
        const int fo = tid - 384;
        const float* cw = Wc + li * F_ * F_;
        float a = bc[li * F_ + fo];
#pragma unroll
        for (int fi = 0; fi < F_; ++fi)
            a += cs[(bt - dil) * F_ + fi] * cw[fi * F_ + fo];
        sbase[1][fo] = a;
    }
    // stage x_cur tile
    for (int idx = tid; idx < F_ * nb4; idx += 512) {
        int f = idx / nb4, j4 = idx % nb4;
        ((float4*)&A[f][0])[j4] =
            *(const float4*)(xin + ((size_t)bt * F_ + f) * N_ + nbase + 4 * j4);
    }
    __syncthreads();

    const int n = tid & 127, q = tid >> 7;
    const int gn = nbase + n;
    const bool valid = (gn < N_);
    const int fo0 = q * 8;

    // residual copy (before A is overwritten) + g_cur into Bt
    float rv[8], gc[8];
#pragma unroll
    for (int jj = 0; jj < 8; ++jj) {
        rv[jj] = A[fo0 + jj][n];
        gc[jj] = sbase[0][fo0 + jj];
    }
#pragma unroll
    for (int fi = 0; fi < F_; ++fi) {
        float xv = A[fi][n];
#pragma unroll
        for (int jj = 0; jj < 8; ++jj) gc[jj] += xv * sWc[fi * F_ + fo0 + jj];
    }
#pragma unroll
    for (int jj = 0; jj < 8; ++jj) Bt[fo0 + jj][n] = sigmoidf_(gc[jj]);

    if (hasprev) {
        __syncthreads();  // all reads of A (x_cur) complete
        for (int idx = tid; idx < F_ * nb4; idx += 512) {
            int f = idx / nb4, j4 = idx % nb4;
            ((float4*)&A[f][0])[j4] = *(const float4*)(
                xin + ((size_t)(bt - dil) * F_ + f) * N_ + nbase + 4 * j4);
        }
        __syncthreads();
        float gp[8];
#pragma unroll
        for (int jj = 0; jj < 8; ++jj) gp[jj] = sbase[1][fo0 + jj];
#pragma unroll
        for (int fi = 0; fi < F_; ++fi) {
            float xv = A[fi][n];
#pragma unroll
            for (int jj = 0; jj < 8; ++jj) gp[jj] += xv * sWc[fi * F_ + fo0 + jj];
        }
        __syncthreads();  // all reads of A (x_prev) complete before overwrite
#pragma unroll
        for (int jj = 0; jj < 8; ++jj) A[fo0 + jj][n] = sigmoidf_(gp[jj]);
    }
    __syncthreads();  // Bt (and A = g_prev if hasprev) ready

    // conv: out = relu(bias + sum_fi gprev*w0 + gcur*w1)
    float acc[8];
#pragma unroll
    for (int jj = 0; jj < 8; ++jj) acc[jj] = sB[fo0 + jj];
    if (hasprev) {
#pragma unroll
        for (int fi = 0; fi < F_; ++fi) {
            float gpv = A[fi][n], gcv = Bt[fi][n];
#pragma unroll
            for (int jj = 0; jj < 8; ++jj)
                acc[jj] += gpv * sW[((fo0 + jj) * F_ + fi) * K_ + 0]
                         + gcv * sW[((fo0 + jj) * F_ + fi) * K_ + 1];
        }
    } else {
#pragma unroll
        for (int fi = 0; fi < F_; ++fi) {
            float gcv = Bt[fi][n];
#pragma unroll
            for (int jj = 0; jj < 8; ++jj)
                acc[jj] += gcv * sW[((fo0 + jj) * F_ + fi) * K_ + 1];
        }
    }

    float xov[8];
#pragma unroll
    for (int jj = 0; jj < 8; ++jj) xov[jj] = 0.f;
    if (valid) {
#pragma unroll
        for (int jj = 0; jj < 8; ++jj) {
            float o = fmaxf(acc[jj], 0.f);
            float xo = o + rv[jj];
            if (xout) xout[((size_t)bt * F_ + fo0 + jj) * N_ + gn] = xo;
            acc[jj] = o;   // relu output for res stash
            xov[jj] = xo;  // for colsum
        }
        if (t == T_ - 1) {
            float* rs = resP + ((size_t)(li * B_ + b) * N_ + gn) * F_ + fo0;
#pragma unroll
            for (int jj = 0; jj < 8; ++jj) rs[jj] = acc[jj];
        }
    }

    // colsum of xout for next layer (invalid lanes contribute 0)
    if (do_cs) {
        const int lane = tid & 63;
#pragma unroll
        for (int jj = 0; jj < 8; ++jj) {
            float s = xov[jj];
#pragma unroll
            for (int off = 32; off >= 1; off >>= 1) s += __shfl_xor(s, off, 64);
            if (lane == 0) atomicAdd(&cs_next[bt * F_ + fo0 + jj], s);
        }
    }
}

// ---------------------------------------------------------------------------
// Fused attention (PASSED r4/r7). grid = B_*N_/2 (4000) blocks x 192 threads.
// res layout resP[l][b][n][f]. Stage 1: 6 groups of 32 lanes compute
// score(b,l,n) with the reference's reshape quirk (j=n*3+l -> l'=j/500,
// n'=j%500). Stage 2: softmax over L + weighted combine.
// ---------------------------------------------------------------------------
__global__ __launch_bounds__(192) void att_kernel(
        const float* __restrict__ resP,
        const float* __restrict__ Wa, const float* __restrict__ ba,
        const float* __restrict__ v, float* __restrict__ out) {
    __shared__ __align__(16) float sWa[F_ * F_];
    __shared__ float sScore[2][L_];
    const int tid = threadIdx.x;
    for (int idx = tid; idx < F_ * F_; idx += 192) sWa[idx] = Wa[idx];
    __syncthreads();

    const int pair = blockIdx.x;
    const int b = pair / 250;
    const int base_n = (pair % 250) * 2;
    const int gIdx = tid >> 5;  // 0..5
    const int fo = tid & 31;
    const int o = gIdx / 3, l = gIdx % 3;
    const int n = base_n + o;
    const int j = n * 3 + l;
    const int lp = j / N_, np = j % N_;

    const float vv = v[fo];
    const float* r = resP + ((size_t)(lp * B_ + b) * N_ + np) * F_;
    float acc = ba[fo];
#pragma unroll
    for (int f = 0; f < F_; ++f) acc += r[f] * sWa[f * F_ + fo];
    float s = tanhf(acc) * vv;
#pragma unroll
    for (int off = 16; off >= 1; off >>= 1) s += __shfl_xor(s, off, 64);
    if (fo == 0) sScore[o][l] = s;
    __syncthreads();

    if (tid < 64) {
        const int oo = tid >> 5, f = tid & 31;
        const int nn = base_n + oo;
        const float s0 = sScore[oo][0], s1 = sScore[oo][1], s2 = sScore[oo][2];
        const float m = fmaxf(fmaxf(s0, s1), s2);
        const float e0 = __expf(s0 - m), e1 = __expf(s1 - m), e2 = __expf(s2 - m);
        const float inv = 1.f / (e0 + e1 + e2);
        const float r0 = resP[((size_t)(0 * B_ + b) * N_ + nn) * F_ + f];
        const float r1 = resP[((size_t)(1 * B_ + b) * N_ + nn) * F_ + f];
        const float r2 = resP[((size_t)(2 * B_ + b) * N_ + nn) * F_ + f];
        out[(size_t)(b * N_ + nn) * F_ + f] = (e0 * r0 + e1 * r1 + e2 * r2) * inv;
    }
}

// ---------------------------------------------------------------------------
extern "C" void kernel_launch(void* const* d_in, const int* in_sizes, int n_in,
                              void* d_out, int out_size, void* d_ws, size_t ws_size,
                              hipStream_t stream) {
    const float* x0      = (const float*)d_in[0];   // node_embeddings (B,T,F,N)
    const float* conv_w  = (const float*)d_in[4];   // (L,F,F,1,K)
    const float* conv_b  = (const float*)d_in[5];   // (L,F)
    const float* gcn_w   = (const float*)d_in[6];   // (L,F,F)
    const float* gcn_b   = (const float*)d_in[7];   // (L,F)
    const float* gate_w  = (const float*)d_in[8];   // (F,F)
    const float* gate_b  = (const float*)d_in[9];   // (F,)
    const float* att_Wa  = (const float*)d_in[10];  // (F,F)
    const float* att_ba  = (const float*)d_in[11];  // (F,)
    const float* att_v   = (const float*)d_in[12];  // (F,1)

    float* ws = (float*)d_ws;
    float* xA   = ws;               // B*T*F*N = 3,072,000
    float* xB   = xA + 3072000;     // 3,072,000
    float* resP = xB + 3072000;     // L*B*N*F = 768,000
    float* Wc   = resP + 768000;    // 3*32*32 = 3072
    float* bc   = Wc + 3072;        // 96
    float* cs0  = bc + 96;          // B*T*F = 6144
    float* cs1  = cs0 + 6144;       // 6144
    float* cs2  = cs1 + 6144;       // 6144
    // total ~28 MB

    prep_kernel<<<B_ * T_, 256, 0, stream>>>(x0, gcn_w, gcn_b, gate_w, gate_b,
                                             Wc, bc, cs0, cs1, cs2);

    // Active-timestep cone: only out[t=11] is consumed per layer.
    // L0: t in {5,7,9,11} (produces x1 + cs1 there, resP0 at t=11)
    // L1: t in {7,11}     (produces x2 + cs2 there, resP1 at t=11)
    // L2: t = 11 only     (resP2; xout unconsumed -> nullptr)
    layer_kernel<<<B_ * 4 * 4, 512, 0, stream>>>(x0, xA, conv_w, conv_b,
                                                 Wc, bc, cs0, 0, 1,
                                                 resP, cs1, 1, 5, 2, 4);
    layer_kernel<<<B_ * 2 * 4, 512, 0, stream>>>(xA, xB, conv_w, conv_b,
                                                 Wc, bc, cs1, 1, 2,
                                                 resP, cs2, 1, 7, 4, 2);
    layer_kernel<<<B_ * 1 * 4, 512, 0, stream>>>(xB, (float*)nullptr, conv_w, conv_b,
                                                 Wc, bc, cs2, 2, 4,
                                                 resP, cs1, 0, 11, 1, 1);

    att_kernel<<<(B_ * N_) / 2, 192, 0, stream>>>(resP, att_Wa, att_ba, att_v,
                                                  (float*)d_out);
}